// Round 8
// baseline (105.528 us; speedup 1.0000x reference)
//
#include <hip/hip_runtime.h>
#include <math.h>

#define SRATE 32000.f
#define NB 128            // batch rows
#define NT 160000         // samples per row
#define CL 100            // samples per chunk (400B, 16B-aligned)
#define NCROW 1600        // chunks per row
#define SEG 25            // chunks per lane in eq_b scan (NCROW/64)
#define RECROW (NCROW*8)  // floats per row in eoT/sgD
#define NCHUNK (NB*NCROW) // 204800 total chunks
#define ABLK 256          // threads per block in eq_a/eq_c
#define AGRID (NCHUNK/ABLK) // 800 blocks

#ifndef M_PI
#define M_PI 3.14159265358979323846
#endif

// f32 coefficients, reference formula (hardware transcendentals).
__device__ __forceinline__ void coeffs_f32(
    const float* fr, const float* gn, const float* qs, float* c)
{
  #pragma unroll
  for (int f = 0; f < 3; ++f) {
    float w0 = 2.f * (float)M_PI * fr[f] / SRATE;
    float A  = expf(gn[f] * (2.302585093f / 40.f));   // 10^(g/40)
    float al = sinf(w0) / (2.f * qs[f]);
    float cw = cosf(w0);
    float a0 = 1.f + al / A;
    c[f*5+0] = (1.f + al*A) / a0;
    c[f*5+1] = -2.f * cw / a0;
    c[f*5+2] = (1.f - al*A) / a0;
    c[f*5+3] = -2.f * cw / a0;
    c[f*5+4] = (1.f - al/A) / a0;
  }
}

// one cascade step; res <- y3 (pre-shift)
#define STEPR(xn, res) do { \
    float y1 = c[0]*(xn) + c[1]*x1  + c[2]*x2   - c[3]*y1p  - c[4]*y1pp;  \
    float y2 = c[5]*y1  + c[6]*y1p + c[7]*y1pp - c[8]*y2p  - c[9]*y2pp;   \
    float y3 = c[10]*y2 + c[11]*y2p + c[12]*y2pp - c[13]*y3p - c[14]*y3pp;\
    (res) = y3;                                                            \
    x2 = x1; x1 = (xn);                                                    \
    y1pp=y1p; y1p=y1; y2pp=y2p; y2p=y2; y3pp=y3p; y3p=y3;                  \
  } while (0)

#define LDG5(S, base) \
  S##0 = xp[(base)];   S##1 = xp[(base)+1]; S##2 = xp[(base)+2]; \
  S##3 = xp[(base)+3]; S##4 = xp[(base)+4];

#define PRC4(v) do { float d_; STEPR(v.x, d_); (void)d_; STEPR(v.y, d_); \
                     STEPR(v.z, d_); STEPR(v.w, d_); } while (0)
#define PRC5(S) PRC4(S##0); PRC4(S##1); PRC4(S##2); PRC4(S##3); PRC4(S##4);

#define PRC4Y(v, idx) do { float4 o_; STEPR(v.x, o_.x); STEPR(v.y, o_.y); \
                           STEPR(v.z, o_.z); STEPR(v.w, o_.w);            \
                           yp[(idx)] = o_; } while (0)
#define PRC5Y(S, base) PRC4Y(S##0,(base)); PRC4Y(S##1,(base)+1); \
                       PRC4Y(S##2,(base)+2); PRC4Y(S##3,(base)+3); \
                       PRC4Y(S##4,(base)+4);

// ---------------------------------------------------------------------------
// A: register-streaming zero-entry-state cascade, one chunk per thread.
// No LDS -> occupancy bound only by VGPRs (16+ waves/CU). Exit record
// (8 floats) in TRANSPOSED layout eoT[row][plane=ci%SEG][slot=ci/SEG].
// ---------------------------------------------------------------------------
__global__ __launch_bounds__(ABLK, 4) void eq_a(
    const float* __restrict__ x, const float* __restrict__ fr,
    const float* __restrict__ gn, const float* __restrict__ qs,
    float* __restrict__ eoT)
{
  const int gch = blockIdx.x * ABLK + threadIdx.x;
  const int row = gch / NCROW, ci = gch % NCROW;
  float c[15];
  coeffs_f32(fr, gn, qs, c);
  const float4* xp = (const float4*)(x + (size_t)gch * CL);
  float x1 = 0.f, x2 = 0.f;
  if (ci != 0) {
    float2 h = *(const float2*)(x + (size_t)gch * CL - 2);
    x1 = h.y; x2 = h.x;
  }
  float y1p=0,y1pp=0,y2p=0,y2pp=0,y3p=0,y3pp=0;
  float4 A0,A1,A2,A3,A4, B0,B1,B2,B3,B4;
  LDG5(A, 0);
  LDG5(B, 5);   PRC5(A);
  LDG5(A, 10);  PRC5(B);
  LDG5(B, 15);  PRC5(A);
  LDG5(A, 20);  PRC5(B);
  PRC5(A);
  const int plane = ci % SEG, slot = ci / SEG;
  float* ep = eoT + (size_t)row * RECROW + ((size_t)(plane*64 + slot))*8;
  float4 r0; r0.x=y1p; r0.y=y1pp; r0.z=y2p; r0.w=y2pp;
  float4 r1; r1.x=y3p; r1.y=y3pp; r1.z=0.f; r1.w=0.f;
  *(float4*)ep = r0; *(float4*)(ep+4) = r1;
}

// ---------------------------------------------------------------------------
// B: one 64-lane block per row. Prologue (f64): Hc = M^CL, G[k] = Hc^(SEG*2^k).
// 64-lane Kogge-Stone over 1600 chunk-exits; write TRUE entry states to
// sgD[row][chunk] (direct layout -> eq_c reads coalesced). (verified r2/r7)
// ---------------------------------------------------------------------------
__global__ __launch_bounds__(64) void eq_b(
    const float* __restrict__ fr, const float* __restrict__ gn,
    const float* __restrict__ qs, const float* __restrict__ eoT,
    float* __restrict__ sgD)
{
  __shared__ double Mb[36], Rb[36], Tb[36];
  __shared__ float Hs[36], Gs[6*36];
  const int l = threadIdx.x, row = blockIdx.x;
  float c[15];
  coeffs_f32(fr, gn, qs, c);
  if (l < 6) {   // one-step homogeneous matrix M, column l
    double s0=0,s1=0,s2=0,s3=0,s4=0,s5=0;
    if (l==0) s0=1; else if (l==1) s1=1; else if (l==2) s2=1;
    else if (l==3) s3=1; else if (l==4) s4=1; else s5=1;
    double y1 = -(double)c[3]*s0 - (double)c[4]*s1;
    double y2 = (double)c[5]*y1 + (double)c[6]*s0 + (double)c[7]*s1
              - (double)c[8]*s2 - (double)c[9]*s3;
    double y3 = (double)c[10]*y2 + (double)c[11]*s2 + (double)c[12]*s3
              - (double)c[13]*s4 - (double)c[14]*s5;
    Mb[0*6+l]=y1; Mb[1*6+l]=s0; Mb[2*6+l]=y2; Mb[3*6+l]=s2; Mb[4*6+l]=y3; Mb[5*6+l]=s4;
  }
  if (l < 36) Rb[l] = ((l % 7) == 0) ? 1.0 : 0.0;
  __syncthreads();
  const int i = l / 6, j = l % 6;
  int e = CL;                                 // Rb = M^CL = Hc
  while (e) {
    if (e & 1) {
      double acc = 0.0;
      if (l < 36) { for (int k = 0; k < 6; ++k) acc += Rb[i*6+k]*Mb[k*6+j]; Tb[l]=acc; }
      __syncthreads();
      if (l < 36) Rb[l] = Tb[l];
      __syncthreads();
    }
    e >>= 1;
    if (e) {
      double acc = 0.0;
      if (l < 36) { for (int k = 0; k < 6; ++k) acc += Mb[i*6+k]*Mb[k*6+j]; Tb[l]=acc; }
      __syncthreads();
      if (l < 36) Mb[l] = Tb[l];
      __syncthreads();
    }
  }
  if (l < 36) { Hs[l] = (float)Rb[l]; Mb[l] = Rb[l]; }
  __syncthreads();
  if (l < 36) Rb[l] = ((l % 7) == 0) ? 1.0 : 0.0;
  __syncthreads();
  e = SEG;                                    // Rb = Hc^SEG
  while (e) {
    if (e & 1) {
      double acc = 0.0;
      if (l < 36) { for (int k = 0; k < 6; ++k) acc += Rb[i*6+k]*Mb[k*6+j]; Tb[l]=acc; }
      __syncthreads();
      if (l < 36) Rb[l] = Tb[l];
      __syncthreads();
    }
    e >>= 1;
    if (e) {
      double acc = 0.0;
      if (l < 36) { for (int k = 0; k < 6; ++k) acc += Mb[i*6+k]*Mb[k*6+j]; Tb[l]=acc; }
      __syncthreads();
      if (l < 36) Mb[l] = Tb[l];
      __syncthreads();
    }
  }
  if (l < 36) Gs[l] = (float)Rb[l];
  __syncthreads();
  for (int k = 1; k < 6; ++k) {               // Gs[k] = Gs[k-1]^2
    double acc = 0.0;
    if (l < 36) { for (int m = 0; m < 6; ++m) acc += Rb[i*6+m]*Rb[m*6+j]; Tb[l]=acc; }
    __syncthreads();
    if (l < 36) Rb[l] = Tb[l];
    __syncthreads();
    if (l < 36) Gs[k*36+l] = (float)Rb[l];
    __syncthreads();
  }

  float H[36];
  #pragma unroll
  for (int q = 0; q < 36; ++q) H[q] = Hs[q];
  const float* rbase = eoT + (size_t)row * RECROW;
  float u[6] = {0,0,0,0,0,0};
  for (int jj = 0; jj < SEG; ++jj) {          // local zero-entry scan
    const float* ep = rbase + ((size_t)jj*64 + l)*8;
    float4 r0 = *(const float4*)ep, r1 = *(const float4*)(ep+4);
    float ev[6] = {r0.x,r0.y,r0.z,r0.w,r1.x,r1.y};
    float nu[6];
    #pragma unroll
    for (int q = 0; q < 6; ++q) {
      float a = ev[q];
      #pragma unroll
      for (int m = 0; m < 6; ++m) a += H[q*6+m]*u[m];
      nu[q] = a;
    }
    #pragma unroll
    for (int q = 0; q < 6; ++q) u[q] = nu[q];
  }
  float v6[6];
  #pragma unroll
  for (int q = 0; q < 6; ++q) v6[q] = u[q];
  #pragma unroll
  for (int k = 0; k < 6; ++k) {               // Kogge-Stone
    const float* G = Gs + k*36;
    float o[6];
    #pragma unroll
    for (int q = 0; q < 6; ++q) o[q] = __shfl_up(v6[q], 1u << k, 64);
    if (l >= (1 << k)) {
      float nv[6];
      #pragma unroll
      for (int q = 0; q < 6; ++q) {
        float a = v6[q];
        #pragma unroll
        for (int m = 0; m < 6; ++m) a += G[q*6+m]*o[m];
        nv[q] = a;
      }
      #pragma unroll
      for (int q = 0; q < 6; ++q) v6[q] = nv[q];
    }
  }
  float s[6];
  #pragma unroll
  for (int q = 0; q < 6; ++q) s[q] = __shfl_up(v6[q], 1, 64);
  if (l == 0) {
    #pragma unroll
    for (int q = 0; q < 6; ++q) s[q] = 0.f;
  }
  float* wbase = sgD + (size_t)row * RECROW;
  for (int jj = 0; jj < SEG; ++jj) {          // replay: true entries
    const float* ep = rbase + ((size_t)jj*64 + l)*8;
    float4 r0 = *(const float4*)ep, r1 = *(const float4*)(ep+4);
    float ev[6] = {r0.x,r0.y,r0.z,r0.w,r1.x,r1.y};
    float* wp = wbase + ((size_t)l*SEG + jj)*8;
    float4 w0; w0.x=s[0]; w0.y=s[1]; w0.z=s[2]; w0.w=s[3];
    float4 w1; w1.x=s[4]; w1.y=s[5]; w1.z=0.f; w1.w=0.f;
    *(float4*)wp = w0; *(float4*)(wp+4) = w1;
    float ns[6];
    #pragma unroll
    for (int q = 0; q < 6; ++q) {
      float a = ev[q];
      #pragma unroll
      for (int m = 0; m < 6; ++m) a += H[q*6+m]*s[m];
      ns[q] = a;
    }
    #pragma unroll
    for (int q = 0; q < 6; ++q) s[q] = ns[q];
  }
}

// ---------------------------------------------------------------------------
// C: register-streaming exact cascade with true entry state (coalesced sgD
// read), one chunk per thread; y stored per-group from registers.
// ---------------------------------------------------------------------------
__global__ __launch_bounds__(ABLK, 4) void eq_c(
    const float* __restrict__ x, const float* __restrict__ fr,
    const float* __restrict__ gn, const float* __restrict__ qs,
    const float* __restrict__ sgD, float* __restrict__ y)
{
  const int gch = blockIdx.x * ABLK + threadIdx.x;
  const int row = gch / NCROW, ci = gch % NCROW;
  float c[15];
  coeffs_f32(fr, gn, qs, c);
  const float4* xp = (const float4*)(x + (size_t)gch * CL);
  float4* yp = (float4*)(y + (size_t)gch * CL);
  float x1 = 0.f, x2 = 0.f;
  if (ci != 0) {
    float2 h = *(const float2*)(x + (size_t)gch * CL - 2);
    x1 = h.y; x2 = h.x;
  }
  const float* sp = sgD + (size_t)row * RECROW + (size_t)ci * 8;
  float4 s0 = *(const float4*)sp, s1 = *(const float4*)(sp+4);
  float y1p=s0.x, y1pp=s0.y, y2p=s0.z, y2pp=s0.w, y3p=s1.x, y3pp=s1.y;
  float4 A0,A1,A2,A3,A4, B0,B1,B2,B3,B4;
  LDG5(A, 0);
  LDG5(B, 5);   PRC5Y(A, 0);
  LDG5(A, 10);  PRC5Y(B, 5);
  LDG5(B, 15);  PRC5Y(A, 10);
  LDG5(A, 20);  PRC5Y(B, 15);
  PRC5Y(A, 20);
}

// ws: eoT [0, 6.55MB) | sgD [6.55MB, 13.1MB)  (8-float records)
extern "C" void kernel_launch(void* const* d_in, const int* in_sizes, int n_in,
                              void* d_out, int out_size, void* d_ws, size_t ws_size,
                              hipStream_t stream) {
  const float* clip = (const float*)d_in[0];
  const float* fr   = (const float*)d_in[1];
  const float* gn   = (const float*)d_in[2];
  const float* qs   = (const float*)d_in[3];
  float* out = (float*)d_out;
  float* eoT = (float*)d_ws;
  float* sgD = eoT + (size_t)NB * RECROW;

  eq_a<<<AGRID, ABLK, 0, stream>>>(clip, fr, gn, qs, eoT);
  eq_b<<<NB, 64, 0, stream>>>(fr, gn, qs, eoT, sgD);
  eq_c<<<AGRID, ABLK, 0, stream>>>(clip, fr, gn, qs, sgD, out);
}

// Round 9
// 77.404 us; speedup vs baseline: 1.3633x; 1.3633x over previous
//
#include <hip/hip_runtime.h>
#include <math.h>

#define SRATE 32000.f
#define NB 128            // batch rows
#define NT 160000         // samples per row
#define CL 100            // samples per chunk (400B, 16B-aligned)
#define NCROW 1600        // chunks per row
#define SEG 25            // chunks per lane in eq_b scan (NCROW/64)
#define RECROW (NCROW*8)  // floats per row in eoT/sgD
#define NCHUNK (NB*NCROW) // 204800 total chunks
#define NBLK (NCHUNK/64)  // 3200 blocks of 64 threads

#ifndef M_PI
#define M_PI 3.14159265358979323846
#endif

// f32 coefficients, reference formula (hardware transcendentals).
__device__ __forceinline__ void coeffs_f32(
    const float* fr, const float* gn, const float* qs, float* c)
{
  #pragma unroll
  for (int f = 0; f < 3; ++f) {
    float w0 = 2.f * (float)M_PI * fr[f] / SRATE;
    float A  = expf(gn[f] * (2.302585093f / 40.f));   // 10^(g/40)
    float al = sinf(w0) / (2.f * qs[f]);
    float cw = cosf(w0);
    float a0 = 1.f + al / A;
    c[f*5+0] = (1.f + al*A) / a0;
    c[f*5+1] = -2.f * cw / a0;
    c[f*5+2] = (1.f - al*A) / a0;
    c[f*5+3] = -2.f * cw / a0;
    c[f*5+4] = (1.f - al/A) / a0;
  }
}

// one cascade step; res <- y3 (pre-shift)
#define STEPR(xn, res) do { \
    float y1 = c[0]*(xn) + c[1]*x1  + c[2]*x2   - c[3]*y1p  - c[4]*y1pp;  \
    float y2 = c[5]*y1  + c[6]*y1p + c[7]*y1pp - c[8]*y2p  - c[9]*y2pp;   \
    float y3 = c[10]*y2 + c[11]*y2p + c[12]*y2pp - c[13]*y3p - c[14]*y3pp;\
    (res) = y3;                                                            \
    x2 = x1; x1 = (xn);                                                    \
    y1pp=y1p; y1p=y1; y2pp=y2p; y2p=y2; y3pp=y3p; y3p=y3;                  \
  } while (0)

#define LDG5(S, base) \
  S##0 = xp[(base)];   S##1 = xp[(base)+1]; S##2 = xp[(base)+2]; \
  S##3 = xp[(base)+3]; S##4 = xp[(base)+4];

#define PRC4(v) do { float d_; STEPR(v.x, d_); (void)d_; STEPR(v.y, d_); \
                     STEPR(v.z, d_); STEPR(v.w, d_); } while (0)
#define PRC5(S) PRC4(S##0); PRC4(S##1); PRC4(S##2); PRC4(S##3); PRC4(S##4);

// process float4 -> LDS own row, conflict-free rotation slot ((k+j)&31)
#define PRC4L(v, k) do { float4 o_; STEPR(v.x, o_.x); STEPR(v.y, o_.y);   \
                         STEPR(v.z, o_.z); STEPR(v.w, o_.w);              \
                         *(float4*)(&lds[j*128 + ((((k)+j)&31)<<2)]) = o_;\
                       } while (0)
#define PRC5L(S, base) PRC4L(S##0,(base)); PRC4L(S##1,(base)+1); \
                       PRC4L(S##2,(base)+2); PRC4L(S##3,(base)+3); \
                       PRC4L(S##4,(base)+4);

// ---------------------------------------------------------------------------
// A: register-streaming zero-entry-state cascade, one chunk per thread.
// No LDS -> VGPR-bound occupancy (~20 waves/CU). Exit record (8 floats) in
// TRANSPOSED layout eoT[row][plane=ci%SEG][slot=ci/SEG] (eq_b reads coalesced).
// ---------------------------------------------------------------------------
__global__ __launch_bounds__(64) void eq_a(
    const float* __restrict__ x, const float* __restrict__ fr,
    const float* __restrict__ gn, const float* __restrict__ qs,
    float* __restrict__ eoT)
{
  const int gch = blockIdx.x * 64 + threadIdx.x;
  const int row = gch / NCROW, ci = gch % NCROW;
  float c[15];
  coeffs_f32(fr, gn, qs, c);
  const float4* xp = (const float4*)(x + (size_t)gch * CL);
  float x1 = 0.f, x2 = 0.f;
  if (ci != 0) {
    float2 h = *(const float2*)(x + (size_t)gch * CL - 2);
    x1 = h.y; x2 = h.x;
  }
  float y1p=0,y1pp=0,y2p=0,y2pp=0,y3p=0,y3pp=0;
  float4 A0,A1,A2,A3,A4, B0,B1,B2,B3,B4;
  LDG5(A, 0);
  LDG5(B, 5);   PRC5(A);
  LDG5(A, 10);  PRC5(B);
  LDG5(B, 15);  PRC5(A);
  LDG5(A, 20);  PRC5(B);
  PRC5(A);
  const int plane = ci % SEG, slot = ci / SEG;
  float* ep = eoT + (size_t)row * RECROW + ((size_t)(plane*64 + slot))*8;
  float4 r0; r0.x=y1p; r0.y=y1pp; r0.z=y2p; r0.w=y2pp;
  float4 r1; r1.x=y3p; r1.y=y3pp; r1.z=0.f; r1.w=0.f;
  *(float4*)ep = r0; *(float4*)(ep+4) = r1;
}

// ---------------------------------------------------------------------------
// B: one 64-lane block per row. Prologue (f64): Hc = M^CL, G[k] = Hc^(SEG*2^k).
// 64-lane Kogge-Stone over 1600 chunk-exits; write TRUE entry states to
// sgD[row][chunk] (direct layout -> eq_c reads coalesced). (verified r2/r7/r8)
// ---------------------------------------------------------------------------
__global__ __launch_bounds__(64) void eq_b(
    const float* __restrict__ fr, const float* __restrict__ gn,
    const float* __restrict__ qs, const float* __restrict__ eoT,
    float* __restrict__ sgD)
{
  __shared__ double Mb[36], Rb[36], Tb[36];
  __shared__ float Hs[36], Gs[6*36];
  const int l = threadIdx.x, row = blockIdx.x;
  float c[15];
  coeffs_f32(fr, gn, qs, c);
  if (l < 6) {   // one-step homogeneous matrix M, column l
    double s0=0,s1=0,s2=0,s3=0,s4=0,s5=0;
    if (l==0) s0=1; else if (l==1) s1=1; else if (l==2) s2=1;
    else if (l==3) s3=1; else if (l==4) s4=1; else s5=1;
    double y1 = -(double)c[3]*s0 - (double)c[4]*s1;
    double y2 = (double)c[5]*y1 + (double)c[6]*s0 + (double)c[7]*s1
              - (double)c[8]*s2 - (double)c[9]*s3;
    double y3 = (double)c[10]*y2 + (double)c[11]*s2 + (double)c[12]*s3
              - (double)c[13]*s4 - (double)c[14]*s5;
    Mb[0*6+l]=y1; Mb[1*6+l]=s0; Mb[2*6+l]=y2; Mb[3*6+l]=s2; Mb[4*6+l]=y3; Mb[5*6+l]=s4;
  }
  if (l < 36) Rb[l] = ((l % 7) == 0) ? 1.0 : 0.0;
  __syncthreads();
  const int i = l / 6, j = l % 6;
  int e = CL;                                 // Rb = M^CL = Hc
  while (e) {
    if (e & 1) {
      double acc = 0.0;
      if (l < 36) { for (int k = 0; k < 6; ++k) acc += Rb[i*6+k]*Mb[k*6+j]; Tb[l]=acc; }
      __syncthreads();
      if (l < 36) Rb[l] = Tb[l];
      __syncthreads();
    }
    e >>= 1;
    if (e) {
      double acc = 0.0;
      if (l < 36) { for (int k = 0; k < 6; ++k) acc += Mb[i*6+k]*Mb[k*6+j]; Tb[l]=acc; }
      __syncthreads();
      if (l < 36) Mb[l] = Tb[l];
      __syncthreads();
    }
  }
  if (l < 36) { Hs[l] = (float)Rb[l]; Mb[l] = Rb[l]; }
  __syncthreads();
  if (l < 36) Rb[l] = ((l % 7) == 0) ? 1.0 : 0.0;
  __syncthreads();
  e = SEG;                                    // Rb = Hc^SEG
  while (e) {
    if (e & 1) {
      double acc = 0.0;
      if (l < 36) { for (int k = 0; k < 6; ++k) acc += Rb[i*6+k]*Mb[k*6+j]; Tb[l]=acc; }
      __syncthreads();
      if (l < 36) Rb[l] = Tb[l];
      __syncthreads();
    }
    e >>= 1;
    if (e) {
      double acc = 0.0;
      if (l < 36) { for (int k = 0; k < 6; ++k) acc += Mb[i*6+k]*Mb[k*6+j]; Tb[l]=acc; }
      __syncthreads();
      if (l < 36) Mb[l] = Tb[l];
      __syncthreads();
    }
  }
  if (l < 36) Gs[l] = (float)Rb[l];
  __syncthreads();
  for (int k = 1; k < 6; ++k) {               // Gs[k] = Gs[k-1]^2
    double acc = 0.0;
    if (l < 36) { for (int m = 0; m < 6; ++m) acc += Rb[i*6+m]*Rb[m*6+j]; Tb[l]=acc; }
    __syncthreads();
    if (l < 36) Rb[l] = Tb[l];
    __syncthreads();
    if (l < 36) Gs[k*36+l] = (float)Rb[l];
    __syncthreads();
  }

  float H[36];
  #pragma unroll
  for (int q = 0; q < 36; ++q) H[q] = Hs[q];
  const float* rbase = eoT + (size_t)row * RECROW;
  float u[6] = {0,0,0,0,0,0};
  for (int jj = 0; jj < SEG; ++jj) {          // local zero-entry scan
    const float* ep = rbase + ((size_t)jj*64 + l)*8;
    float4 r0 = *(const float4*)ep, r1 = *(const float4*)(ep+4);
    float ev[6] = {r0.x,r0.y,r0.z,r0.w,r1.x,r1.y};
    float nu[6];
    #pragma unroll
    for (int q = 0; q < 6; ++q) {
      float a = ev[q];
      #pragma unroll
      for (int m = 0; m < 6; ++m) a += H[q*6+m]*u[m];
      nu[q] = a;
    }
    #pragma unroll
    for (int q = 0; q < 6; ++q) u[q] = nu[q];
  }
  float v6[6];
  #pragma unroll
  for (int q = 0; q < 6; ++q) v6[q] = u[q];
  #pragma unroll
  for (int k = 0; k < 6; ++k) {               // Kogge-Stone
    const float* G = Gs + k*36;
    float o[6];
    #pragma unroll
    for (int q = 0; q < 6; ++q) o[q] = __shfl_up(v6[q], 1u << k, 64);
    if (l >= (1 << k)) {
      float nv[6];
      #pragma unroll
      for (int q = 0; q < 6; ++q) {
        float a = v6[q];
        #pragma unroll
        for (int m = 0; m < 6; ++m) a += G[q*6+m]*o[m];
        nv[q] = a;
      }
      #pragma unroll
      for (int q = 0; q < 6; ++q) v6[q] = nv[q];
    }
  }
  float s[6];
  #pragma unroll
  for (int q = 0; q < 6; ++q) s[q] = __shfl_up(v6[q], 1, 64);
  if (l == 0) {
    #pragma unroll
    for (int q = 0; q < 6; ++q) s[q] = 0.f;
  }
  float* wbase = sgD + (size_t)row * RECROW;
  for (int jj = 0; jj < SEG; ++jj) {          // replay: true entries
    const float* ep = rbase + ((size_t)jj*64 + l)*8;
    float4 r0 = *(const float4*)ep, r1 = *(const float4*)(ep+4);
    float ev[6] = {r0.x,r0.y,r0.z,r0.w,r1.x,r1.y};
    float* wp = wbase + ((size_t)l*SEG + jj)*8;
    float4 w0; w0.x=s[0]; w0.y=s[1]; w0.z=s[2]; w0.w=s[3];
    float4 w1; w1.x=s[4]; w1.y=s[5]; w1.z=0.f; w1.w=0.f;
    *(float4*)wp = w0; *(float4*)(wp+4) = w1;
    float ns[6];
    #pragma unroll
    for (int q = 0; q < 6; ++q) {
      float a = ev[q];
      #pragma unroll
      for (int m = 0; m < 6; ++m) a += H[q*6+m]*s[m];
      ns[q] = a;
    }
    #pragma unroll
    for (int q = 0; q < 6; ++q) s[q] = ns[q];
  }
}

// ---------------------------------------------------------------------------
// C: register-streamed reads + exact cascade with true entry state; y staged
// in a 32KB LDS tile (conflict-free rotation) and stored cooperatively
// (1KB contiguous per instruction). One wave per block.
// ---------------------------------------------------------------------------
__global__ __launch_bounds__(64) void eq_c(
    const float* __restrict__ x, const float* __restrict__ fr,
    const float* __restrict__ gn, const float* __restrict__ qs,
    const float* __restrict__ sgD, float* __restrict__ y)
{
  __shared__ float lds[64 * 128];
  const int j = threadIdx.x;
  const int t = blockIdx.x;
  const int gch = t * 64 + j;
  const int row = gch / NCROW, ci = gch % NCROW;
  float c[15];
  coeffs_f32(fr, gn, qs, c);
  const float4* xp = (const float4*)(x + (size_t)gch * CL);
  float x1 = 0.f, x2 = 0.f;
  if (ci != 0) {
    float2 h = *(const float2*)(x + (size_t)gch * CL - 2);
    x1 = h.y; x2 = h.x;
  }
  const float* sp = sgD + (size_t)row * RECROW + (size_t)ci * 8;
  float4 s0 = *(const float4*)sp, s1 = *(const float4*)(sp+4);
  float y1p=s0.x, y1pp=s0.y, y2p=s0.z, y2pp=s0.w, y3p=s1.x, y3pp=s1.y;
  float4 A0,A1,A2,A3,A4, B0,B1,B2,B3,B4;
  LDG5(A, 0);
  LDG5(B, 5);   PRC5L(A, 0);
  LDG5(A, 10);  PRC5L(B, 5);
  LDG5(B, 15);  PRC5L(A, 10);
  LDG5(A, 20);  PRC5L(B, 15);
  PRC5L(A, 20);
  __syncthreads();                      // LDS writes visible (single wave)
  float* yg = y + (size_t)t * (64 * CL);
  #pragma unroll
  for (int it = 0; it < 25; ++it) {     // coalesced: 1KB contiguous/instr
    const int f = it * 64 + j;
    const int s = f / 25, m = f % 25;
    float4 v = *(const float4*)(&lds[s*128 + (((m + s) & 31) << 2)]);
    *(float4*)(yg + 4*f) = v;
  }
}

// ws: eoT [0, 6.55MB) | sgD [6.55MB, 13.1MB)  (8-float records)
extern "C" void kernel_launch(void* const* d_in, const int* in_sizes, int n_in,
                              void* d_out, int out_size, void* d_ws, size_t ws_size,
                              hipStream_t stream) {
  const float* clip = (const float*)d_in[0];
  const float* fr   = (const float*)d_in[1];
  const float* gn   = (const float*)d_in[2];
  const float* qs   = (const float*)d_in[3];
  float* out = (float*)d_out;
  float* eoT = (float*)d_ws;
  float* sgD = eoT + (size_t)NB * RECROW;

  eq_a<<<NBLK, 64, 0, stream>>>(clip, fr, gn, qs, eoT);
  eq_b<<<NB, 64, 0, stream>>>(fr, gn, qs, eoT, sgD);
  eq_c<<<NBLK, 64, 0, stream>>>(clip, fr, gn, qs, sgD, out);
}

// Round 10
// 75.519 us; speedup vs baseline: 1.3974x; 1.0250x over previous
//
#include <hip/hip_runtime.h>
#include <math.h>

#define SRATE 32000.f
#define NB 128            // batch rows
#define NT 160000         // samples per row
#define CL 100            // samples per chunk (400B, 16B-aligned)
#define NCROW 1600        // chunks per row
#define SEG 25            // chunks per lane in eq_b scan (NCROW/64)
#define RECROW (NCROW*8)  // floats per row in eoT/sgD
#define NCHUNK (NB*NCROW) // 204800 total chunks
#define NBLK (NCHUNK/64)  // 3200 blocks of 64 threads

#ifndef M_PI
#define M_PI 3.14159265358979323846
#endif

// f32 coefficients, reference formula (hardware transcendentals).
__device__ __forceinline__ void coeffs_f32(
    const float* fr, const float* gn, const float* qs, float* c)
{
  #pragma unroll
  for (int f = 0; f < 3; ++f) {
    float w0 = 2.f * (float)M_PI * fr[f] / SRATE;
    float A  = expf(gn[f] * (2.302585093f / 40.f));   // 10^(g/40)
    float al = sinf(w0) / (2.f * qs[f]);
    float cw = cosf(w0);
    float a0 = 1.f + al / A;
    c[f*5+0] = (1.f + al*A) / a0;
    c[f*5+1] = -2.f * cw / a0;
    c[f*5+2] = (1.f - al*A) / a0;
    c[f*5+3] = -2.f * cw / a0;
    c[f*5+4] = (1.f - al/A) / a0;
  }
}

// one cascade step; res <- y3 (pre-shift)
#define STEPR(xn, res) do { \
    float y1 = c[0]*(xn) + c[1]*x1  + c[2]*x2   - c[3]*y1p  - c[4]*y1pp;  \
    float y2 = c[5]*y1  + c[6]*y1p + c[7]*y1pp - c[8]*y2p  - c[9]*y2pp;   \
    float y3 = c[10]*y2 + c[11]*y2p + c[12]*y2pp - c[13]*y3p - c[14]*y3pp;\
    (res) = y3;                                                            \
    x2 = x1; x1 = (xn);                                                    \
    y1pp=y1p; y1p=y1; y2pp=y2p; y2p=y2; y3pp=y3p; y3p=y3;                  \
  } while (0)

#define LDG5(S, base) \
  S##0 = xp[(base)];   S##1 = xp[(base)+1]; S##2 = xp[(base)+2]; \
  S##3 = xp[(base)+3]; S##4 = xp[(base)+4];

#define PRC4(v) do { float d_; STEPR(v.x, d_); (void)d_; STEPR(v.y, d_); \
                     STEPR(v.z, d_); STEPR(v.w, d_); } while (0)
#define PRC5(S) PRC4(S##0); PRC4(S##1); PRC4(S##2); PRC4(S##3); PRC4(S##4);

// ---------------------------------------------------------------------------
// A: register-streaming zero-entry-state cascade, one chunk per thread.
// No LDS -> VGPR-bound occupancy. Exit record (8 floats) in TRANSPOSED
// layout eoT[row][plane=ci%SEG][slot=ci/SEG] (eq_b reads coalesced; the
// 32B-scatter writes are L2-absorbed, 6.5MB total).
// ---------------------------------------------------------------------------
__global__ __launch_bounds__(64) void eq_a(
    const float* __restrict__ x, const float* __restrict__ fr,
    const float* __restrict__ gn, const float* __restrict__ qs,
    float* __restrict__ eoT)
{
  const int gch = blockIdx.x * 64 + threadIdx.x;
  const int row = gch / NCROW, ci = gch % NCROW;
  float c[15];
  coeffs_f32(fr, gn, qs, c);
  const float4* xp = (const float4*)(x + (size_t)gch * CL);
  float x1 = 0.f, x2 = 0.f;
  if (ci != 0) {
    float2 h = *(const float2*)(x + (size_t)gch * CL - 2);
    x1 = h.y; x2 = h.x;
  }
  float y1p=0,y1pp=0,y2p=0,y2pp=0,y3p=0,y3pp=0;
  float4 A0,A1,A2,A3,A4, B0,B1,B2,B3,B4;
  LDG5(A, 0);
  LDG5(B, 5);   PRC5(A);
  LDG5(A, 10);  PRC5(B);
  LDG5(B, 15);  PRC5(A);
  LDG5(A, 20);  PRC5(B);
  PRC5(A);
  const int plane = ci % SEG, slot = ci / SEG;
  float* ep = eoT + (size_t)row * RECROW + ((size_t)(plane*64 + slot))*8;
  float4 r0; r0.x=y1p; r0.y=y1pp; r0.z=y2p; r0.w=y2pp;
  float4 r1; r1.x=y3p; r1.y=y3pp; r1.z=0.f; r1.w=0.f;
  *(float4*)ep = r0; *(float4*)(ep+4) = r1;
}

// ---------------------------------------------------------------------------
// B: one 64-lane block per row. Prologue (f64): Hc = M^CL, G[k] = Hc^(SEG*2^k).
// 64-lane Kogge-Stone over 1600 chunk-exits; write TRUE entry states to
// sgD[row][chunk] (direct layout -> eq_c reads coalesced). (verified r2..r9)
// ---------------------------------------------------------------------------
__global__ __launch_bounds__(64) void eq_b(
    const float* __restrict__ fr, const float* __restrict__ gn,
    const float* __restrict__ qs, const float* __restrict__ eoT,
    float* __restrict__ sgD)
{
  __shared__ double Mb[36], Rb[36], Tb[36];
  __shared__ float Hs[36], Gs[6*36];
  const int l = threadIdx.x, row = blockIdx.x;
  float c[15];
  coeffs_f32(fr, gn, qs, c);
  if (l < 6) {   // one-step homogeneous matrix M, column l
    double s0=0,s1=0,s2=0,s3=0,s4=0,s5=0;
    if (l==0) s0=1; else if (l==1) s1=1; else if (l==2) s2=1;
    else if (l==3) s3=1; else if (l==4) s4=1; else s5=1;
    double y1 = -(double)c[3]*s0 - (double)c[4]*s1;
    double y2 = (double)c[5]*y1 + (double)c[6]*s0 + (double)c[7]*s1
              - (double)c[8]*s2 - (double)c[9]*s3;
    double y3 = (double)c[10]*y2 + (double)c[11]*s2 + (double)c[12]*s3
              - (double)c[13]*s4 - (double)c[14]*s5;
    Mb[0*6+l]=y1; Mb[1*6+l]=s0; Mb[2*6+l]=y2; Mb[3*6+l]=s2; Mb[4*6+l]=y3; Mb[5*6+l]=s4;
  }
  if (l < 36) Rb[l] = ((l % 7) == 0) ? 1.0 : 0.0;
  __syncthreads();
  const int i = l / 6, j = l % 6;
  int e = CL;                                 // Rb = M^CL = Hc
  while (e) {
    if (e & 1) {
      double acc = 0.0;
      if (l < 36) { for (int k = 0; k < 6; ++k) acc += Rb[i*6+k]*Mb[k*6+j]; Tb[l]=acc; }
      __syncthreads();
      if (l < 36) Rb[l] = Tb[l];
      __syncthreads();
    }
    e >>= 1;
    if (e) {
      double acc = 0.0;
      if (l < 36) { for (int k = 0; k < 6; ++k) acc += Mb[i*6+k]*Mb[k*6+j]; Tb[l]=acc; }
      __syncthreads();
      if (l < 36) Mb[l] = Tb[l];
      __syncthreads();
    }
  }
  if (l < 36) { Hs[l] = (float)Rb[l]; Mb[l] = Rb[l]; }
  __syncthreads();
  if (l < 36) Rb[l] = ((l % 7) == 0) ? 1.0 : 0.0;
  __syncthreads();
  e = SEG;                                    // Rb = Hc^SEG
  while (e) {
    if (e & 1) {
      double acc = 0.0;
      if (l < 36) { for (int k = 0; k < 6; ++k) acc += Rb[i*6+k]*Mb[k*6+j]; Tb[l]=acc; }
      __syncthreads();
      if (l < 36) Rb[l] = Tb[l];
      __syncthreads();
    }
    e >>= 1;
    if (e) {
      double acc = 0.0;
      if (l < 36) { for (int k = 0; k < 6; ++k) acc += Mb[i*6+k]*Mb[k*6+j]; Tb[l]=acc; }
      __syncthreads();
      if (l < 36) Mb[l] = Tb[l];
      __syncthreads();
    }
  }
  if (l < 36) Gs[l] = (float)Rb[l];
  __syncthreads();
  for (int k = 1; k < 6; ++k) {               // Gs[k] = Gs[k-1]^2
    double acc = 0.0;
    if (l < 36) { for (int m = 0; m < 6; ++m) acc += Rb[i*6+m]*Rb[m*6+j]; Tb[l]=acc; }
    __syncthreads();
    if (l < 36) Rb[l] = Tb[l];
    __syncthreads();
    if (l < 36) Gs[k*36+l] = (float)Rb[l];
    __syncthreads();
  }

  float H[36];
  #pragma unroll
  for (int q = 0; q < 36; ++q) H[q] = Hs[q];
  const float* rbase = eoT + (size_t)row * RECROW;
  float u[6] = {0,0,0,0,0,0};
  for (int jj = 0; jj < SEG; ++jj) {          // local zero-entry scan
    const float* ep = rbase + ((size_t)jj*64 + l)*8;
    float4 r0 = *(const float4*)ep, r1 = *(const float4*)(ep+4);
    float ev[6] = {r0.x,r0.y,r0.z,r0.w,r1.x,r1.y};
    float nu[6];
    #pragma unroll
    for (int q = 0; q < 6; ++q) {
      float a = ev[q];
      #pragma unroll
      for (int m = 0; m < 6; ++m) a += H[q*6+m]*u[m];
      nu[q] = a;
    }
    #pragma unroll
    for (int q = 0; q < 6; ++q) u[q] = nu[q];
  }
  float v6[6];
  #pragma unroll
  for (int q = 0; q < 6; ++q) v6[q] = u[q];
  #pragma unroll
  for (int k = 0; k < 6; ++k) {               // Kogge-Stone
    const float* G = Gs + k*36;
    float o[6];
    #pragma unroll
    for (int q = 0; q < 6; ++q) o[q] = __shfl_up(v6[q], 1u << k, 64);
    if (l >= (1 << k)) {
      float nv[6];
      #pragma unroll
      for (int q = 0; q < 6; ++q) {
        float a = v6[q];
        #pragma unroll
        for (int m = 0; m < 6; ++m) a += G[q*6+m]*o[m];
        nv[q] = a;
      }
      #pragma unroll
      for (int q = 0; q < 6; ++q) v6[q] = nv[q];
    }
  }
  float s[6];
  #pragma unroll
  for (int q = 0; q < 6; ++q) s[q] = __shfl_up(v6[q], 1, 64);
  if (l == 0) {
    #pragma unroll
    for (int q = 0; q < 6; ++q) s[q] = 0.f;
  }
  float* wbase = sgD + (size_t)row * RECROW;
  for (int jj = 0; jj < SEG; ++jj) {          // replay: true entries
    const float* ep = rbase + ((size_t)jj*64 + l)*8;
    float4 r0 = *(const float4*)ep, r1 = *(const float4*)(ep+4);
    float ev[6] = {r0.x,r0.y,r0.z,r0.w,r1.x,r1.y};
    float* wp = wbase + ((size_t)l*SEG + jj)*8;
    float4 w0; w0.x=s[0]; w0.y=s[1]; w0.z=s[2]; w0.w=s[3];
    float4 w1; w1.x=s[4]; w1.y=s[5]; w1.z=0.f; w1.w=0.f;
    *(float4*)wp = w0; *(float4*)(wp+4) = w1;
    float ns[6];
    #pragma unroll
    for (int q = 0; q < 6; ++q) {
      float a = ev[q];
      #pragma unroll
      for (int m = 0; m < 6; ++m) a += H[q*6+m]*s[m];
      ns[q] = a;
    }
    #pragma unroll
    for (int q = 0; q < 6; ++q) s[q] = ns[q];
  }
}

// ---------------------------------------------------------------------------
// C: full LDS pipeline, 25.6KB tile (64 chunks x 100 floats, linear stride
// 100 -> bank 4(j+k) mod 32 = exactly the b128 8-word/bank floor, no swizzle
// needed). coop-load x (1KB/instr) -> per-thread IIR on own row (in-place
// y) -> coop-store y. One wave per block; ~6 blocks/CU.
// ---------------------------------------------------------------------------
__global__ __launch_bounds__(64) void eq_c(
    const float* __restrict__ x, const float* __restrict__ fr,
    const float* __restrict__ gn, const float* __restrict__ qs,
    const float* __restrict__ sgD, float* __restrict__ y)
{
  __shared__ float lds[64 * CL];        // 25.6 KB
  const int j = threadIdx.x;
  const int t = blockIdx.x;
  const int gch = t * 64 + j;
  const int row = gch / NCROW, ci = gch % NCROW;
  float c[15];
  coeffs_f32(fr, gn, qs, c);
  const float* xg = x + (size_t)t * (64 * CL);
  #pragma unroll
  for (int it = 0; it < 25; ++it) {     // coalesced: 1KB contiguous/instr
    const int f = it * 64 + j;
    float4 v = *(const float4*)(xg + 4*f);
    *(float4*)(&lds[4*f]) = v;
  }
  __syncthreads();
  // boundary x-history: lane j>0 from neighbor's LDS row (read before any
  // overwrite; single wave => program-ordered), lane 0 from global.
  float x1, x2;
  if (j == 0) {
    if (ci == 0) { x1 = 0.f; x2 = 0.f; }
    else { float2 h = *(const float2*)(xg - 2); x1 = h.y; x2 = h.x; }
  } else {
    x1 = lds[(j-1)*CL + 99];
    x2 = lds[(j-1)*CL + 98];
  }
  const float* sp = sgD + (size_t)row * RECROW + (size_t)ci * 8;
  float4 s0 = *(const float4*)sp, s1 = *(const float4*)(sp+4);
  float y1p=s0.x, y1pp=s0.y, y2p=s0.z, y2pp=s0.w, y3p=s1.x, y3pp=s1.y;
  float* myrow = &lds[j * CL];
  #pragma unroll
  for (int k = 0; k < 25; ++k) {
    float4 xv = *(const float4*)(myrow + 4*k);
    float4 o_;
    STEPR(xv.x, o_.x); STEPR(xv.y, o_.y);
    STEPR(xv.z, o_.z); STEPR(xv.w, o_.w);
    *(float4*)(myrow + 4*k) = o_;       // own row: in-place y
  }
  __syncthreads();
  float* yg = y + (size_t)t * (64 * CL);
  #pragma unroll
  for (int it = 0; it < 25; ++it) {     // coalesced: 1KB contiguous/instr
    const int f = it * 64 + j;
    float4 v = *(const float4*)(&lds[4*f]);
    *(float4*)(yg + 4*f) = v;
  }
}

// ws: eoT [0, 6.55MB) | sgD [6.55MB, 13.1MB)  (8-float records)
extern "C" void kernel_launch(void* const* d_in, const int* in_sizes, int n_in,
                              void* d_out, int out_size, void* d_ws, size_t ws_size,
                              hipStream_t stream) {
  const float* clip = (const float*)d_in[0];
  const float* fr   = (const float*)d_in[1];
  const float* gn   = (const float*)d_in[2];
  const float* qs   = (const float*)d_in[3];
  float* out = (float*)d_out;
  float* eoT = (float*)d_ws;
  float* sgD = eoT + (size_t)NB * RECROW;

  eq_a<<<NBLK, 64, 0, stream>>>(clip, fr, gn, qs, eoT);
  eq_b<<<NB, 64, 0, stream>>>(fr, gn, qs, eoT, sgD);
  eq_c<<<NBLK, 64, 0, stream>>>(clip, fr, gn, qs, sgD, out);
}